// Round 1
// baseline (1608.899 us; speedup 1.0000x reference)
//
#include <hip/hip_runtime.h>
#include <hip/hip_bf16.h>
#include <cstdint>

// Problem constants (fixed shapes from the reference)
#define NB 64
#define LQ 256
#define LD 512
#define HD 768
#define QD_ELEMS (NB * LQ)          // 16384
#define DD_ELEMS (NB * LD)          // 32768
#define CELEMS   (LQ * LD)          // 131072 per batch
#define CTOTAL   ((size_t)NB * CELEMS)  // 8388608

// ---------------------------------------------------------------------------
// Kernel: per-row inverse L2 norm (one wave per row of HD=768)
// ---------------------------------------------------------------------------
__global__ __launch_bounds__(256) void rownorm_kernel(const float* __restrict__ x,
                                                      float* __restrict__ inv,
                                                      int rows) {
    int row = blockIdx.x * 4 + (threadIdx.x >> 6);
    int lane = threadIdx.x & 63;
    if (row >= rows) return;
    const float* p = x + (size_t)row * HD;
    float s = 0.f;
#pragma unroll
    for (int i = 0; i < HD / 64; ++i) {
        float v = p[lane + i * 64];
        s += v * v;
    }
#pragma unroll
    for (int off = 32; off; off >>= 1) s += __shfl_down(s, off);
    if (lane == 0) inv[row] = 1.0f / fmaxf(sqrtf(s), 1e-12f);
}

// ---------------------------------------------------------------------------
// Kernel: mask -> distribution (dist = mask / sum(mask)), one block per batch
// ---------------------------------------------------------------------------
__global__ __launch_bounds__(256) void mass_kernel(const float* __restrict__ mask,
                                                   float* __restrict__ dist,
                                                   int L) {
    int b = blockIdx.x;
    int tid = threadIdx.x;
    const float* m = mask + (size_t)b * L;
    float s = 0.f;
    for (int i = tid; i < L; i += 256) s += m[i];
    __shared__ float red[256];
    red[tid] = s;
    __syncthreads();
    for (int st = 128; st; st >>= 1) {
        if (tid < st) red[tid] += red[tid + st];
        __syncthreads();
    }
    float total = red[0];
    for (int i = tid; i < L; i += 256) dist[(size_t)b * L + i] = m[i] / total;
}

// ---------------------------------------------------------------------------
// Kernel: batched GEMM  C[b,q,d] = 1 - (qe[b,q,:]. de[b,d,:]) * qinv * dinv
// 64x64 tile, 256 threads, 4x4 per thread, f32. Also atomicMax per-batch C max.
// ---------------------------------------------------------------------------
__global__ __launch_bounds__(256) void gemm_c_kernel(const float* __restrict__ qe,
                                                     const float* __restrict__ de,
                                                     const float* __restrict__ qinv,
                                                     const float* __restrict__ dinv,
                                                     float* __restrict__ Cout,
                                                     unsigned int* __restrict__ cmax) {
    const int b = blockIdx.z;
    const int m0 = blockIdx.y * 64;
    const int n0 = blockIdx.x * 64;
    const float* A = qe + (size_t)b * LQ * HD;
    const float* Bp = de + (size_t)b * LD * HD;

    __shared__ float As[16][64];
    __shared__ float Bs[16][64];

    float acc[4][4] = {};
    const int tid = threadIdx.x;
    const int tm = tid >> 4, tn = tid & 15;

    for (int k0 = 0; k0 < HD; k0 += 16) {
#pragma unroll
        for (int i = 0; i < 4; ++i) {
            int idx = tid + i * 256;
            int r = idx >> 4, c = idx & 15;
            As[c][r] = A[(size_t)(m0 + r) * HD + k0 + c];
            Bs[c][r] = Bp[(size_t)(n0 + r) * HD + k0 + c];
        }
        __syncthreads();
#pragma unroll
        for (int k = 0; k < 16; ++k) {
            float av[4], bv[4];
#pragma unroll
            for (int i = 0; i < 4; ++i) av[i] = As[k][tm * 4 + i];
#pragma unroll
            for (int j = 0; j < 4; ++j) bv[j] = Bs[k][tn * 4 + j];
#pragma unroll
            for (int i = 0; i < 4; ++i)
#pragma unroll
                for (int j = 0; j < 4; ++j) acc[i][j] += av[i] * bv[j];
        }
        __syncthreads();
    }

    float qi[4], di[4];
#pragma unroll
    for (int i = 0; i < 4; ++i) qi[i] = qinv[(size_t)b * LQ + m0 + tm * 4 + i];
#pragma unroll
    for (int j = 0; j < 4; ++j) di[j] = dinv[(size_t)b * LD + n0 + tn * 4 + j];

    float lmax = -1e30f;
    float* Cb = Cout + (size_t)b * CELEMS;
#pragma unroll
    for (int i = 0; i < 4; ++i) {
        float4 cv;
        float* cp = (float*)&cv;
#pragma unroll
        for (int j = 0; j < 4; ++j) {
            float c = 1.0f - acc[i][j] * qi[i] * di[j];
            cp[j] = c;
            lmax = fmaxf(lmax, c);
        }
        *reinterpret_cast<float4*>(Cb + (size_t)(m0 + tm * 4 + i) * LD + n0 + tn * 4) = cv;
    }

    __shared__ float red[256];
    red[tid] = lmax;
    __syncthreads();
    for (int st = 128; st; st >>= 1) {
        if (tid < st) red[tid] = fmaxf(red[tid], red[tid + st]);
        __syncthreads();
    }
    if (tid == 0) atomicMax(cmax + b, __float_as_uint(red[0]));
}

// ---------------------------------------------------------------------------
// Kernel: K = exp(-C / cmax) stored bf16 (REG = 1)
// ---------------------------------------------------------------------------
__global__ __launch_bounds__(256) void expk_kernel(const float4* __restrict__ C4,
                                                   const unsigned int* __restrict__ cmax,
                                                   ushort4* __restrict__ K4) {
    size_t t = (size_t)blockIdx.x * 256 + threadIdx.x;  // 2097152 total
    int b = (int)(t >> 15);  // (t*4) >> 17
    float inv = -1.0f / __uint_as_float(cmax[b]);
    float4 c = C4[t];
    __hip_bfloat16 h0 = __float2bfloat16(expf(c.x * inv));
    __hip_bfloat16 h1 = __float2bfloat16(expf(c.y * inv));
    __hip_bfloat16 h2 = __float2bfloat16(expf(c.z * inv));
    __hip_bfloat16 h3 = __float2bfloat16(expf(c.w * inv));
    ushort4 o;
    o.x = *reinterpret_cast<unsigned short*>(&h0);
    o.y = *reinterpret_cast<unsigned short*>(&h1);
    o.z = *reinterpret_cast<unsigned short*>(&h2);
    o.w = *reinterpret_cast<unsigned short*>(&h3);
    K4[t] = o;
}

// ---------------------------------------------------------------------------
// Kernel: persistent Sinkhorn — one workgroup per batch, nit iterations.
// v = ddist / (K^T u); u = qdist / (K v). K is bf16, L2-resident per XCD.
// ---------------------------------------------------------------------------
__global__ __launch_bounds__(1024) void sinkhorn_kernel(const __hip_bfloat16* __restrict__ Kmat,
                                                        const float* __restrict__ qdist,
                                                        const float* __restrict__ ddist,
                                                        const int* __restrict__ nitp,
                                                        float* __restrict__ uout,
                                                        float* __restrict__ vout) {
    const int b = blockIdx.x;
    const int tid = threadIdx.x;
    __shared__ float us[LQ], vs[LD], qd[LQ], dd[LD], part[1024];
    const __hip_bfloat16* Kb = Kmat + (size_t)b * CELEMS;

    if (tid < LQ) {
        us[tid] = 1.0f;
        qd[tid] = qdist[(size_t)b * LQ + tid];
    }
    if (tid < LD) dd[tid] = ddist[(size_t)b * LD + tid];
    __syncthreads();

    const int nit = *nitp;
    const int d = tid & (LD - 1);
    const int half = tid >> 9;       // 0 or 1
    const int q0 = half * (LQ / 2);  // 0 or 128
    const int wv = tid >> 6;         // wave id 0..15
    const int lane = tid & 63;

    for (int it = 0; it < nit; ++it) {
        // ---- v-step: v[d] = dd[d] / sum_q K[q][d] * u[q]  (split q over 2 halves)
        float s = 0.f;
        const __hip_bfloat16* col = Kb + (size_t)q0 * LD + d;
#pragma unroll 8
        for (int q = 0; q < LQ / 2; ++q) s += __bfloat162float(col[(size_t)q * LD]) * us[q0 + q];
        part[tid] = s;
        __syncthreads();
        if (tid < LD) vs[tid] = dd[tid] / (part[tid] + part[tid + LD]);
        __syncthreads();

        // ---- u-step: u[q] = qd[q] / sum_d K[q][d] * v[d]  (one wave per row)
        for (int q = wv; q < LQ; q += 16) {
            const __hip_bfloat16* row = Kb + (size_t)q * LD;
            float r = 0.f;
#pragma unroll
            for (int ss = 0; ss < LD / 64; ++ss) {
                int dj = ss * 64 + lane;
                r += __bfloat162float(row[dj]) * vs[dj];
            }
#pragma unroll
            for (int off = 32; off; off >>= 1) r += __shfl_down(r, off);
            if (lane == 0) us[q] = qd[q] / r;
        }
        __syncthreads();
    }

    if (tid < LQ) uout[(size_t)b * LQ + tid] = us[tid];
    if (tid < LD) vout[(size_t)b * LD + tid] = (nit > 0) ? vs[tid] : 0.0f;
}

// ---------------------------------------------------------------------------
// Kernel: T = u*K*v, partial distances = sum(C*T) per (batch, chunk)
// grid (4, NB), 256 threads
// ---------------------------------------------------------------------------
__global__ __launch_bounds__(256) void tdist_kernel(const float* __restrict__ C,
                                                    const __hip_bfloat16* __restrict__ K,
                                                    const float* __restrict__ u,
                                                    const float* __restrict__ v,
                                                    float* __restrict__ T,
                                                    float* __restrict__ part) {
    const int b = blockIdx.y;
    const int ch = blockIdx.x;
    const int tid = threadIdx.x;
    __shared__ float us[LQ], vs[LD];
    us[tid] = u[(size_t)b * LQ + tid];
    vs[tid] = v[(size_t)b * LD + tid];
    vs[tid + 256] = v[(size_t)b * LD + 256 + tid];
    __syncthreads();

    const __hip_bfloat16* Kb = K + (size_t)b * CELEMS;
    const float* Cb = C + (size_t)b * CELEMS;
    float* Tb = T + (size_t)b * CELEMS;

    float local = 0.f;
    const int chunk = CELEMS / 4;  // 32768
    for (int i = tid; i < chunk; i += 256) {
        int e = ch * chunk + i;
        int q = e >> 9;
        int dj = e & (LD - 1);
        float kk = __bfloat162float(Kb[e]);
        float t = us[q] * kk * vs[dj];
        Tb[e] = t;
        local += Cb[e] * t;
    }

    __shared__ float red[256];
    red[tid] = local;
    __syncthreads();
    for (int st = 128; st; st >>= 1) {
        if (tid < st) red[tid] += red[tid + st];
        __syncthreads();
    }
    if (tid == 0) part[b * 4 + ch] = red[0];
}

__global__ void final_dist_kernel(const float* __restrict__ part, float* __restrict__ dist) {
    int b = threadIdx.x;
    if (b < NB) dist[b] = part[b * 4] + part[b * 4 + 1] + part[b * 4 + 2] + part[b * 4 + 3];
}

// ---------------------------------------------------------------------------
extern "C" void kernel_launch(void* const* d_in, const int* in_sizes, int n_in,
                              void* d_out, int out_size, void* d_ws, size_t ws_size,
                              hipStream_t stream) {
    const float* qe = (const float*)d_in[0];
    const float* qmask = (const float*)d_in[1];
    const float* de = (const float*)d_in[2];
    const float* dmask = (const float*)d_in[3];
    const int* nit = (const int*)d_in[4];

    float* out = (float*)d_out;
    float* dist = out;
    float* Cout = out + 64;
    float* Tout = out + 64 + CTOTAL;

    // Workspace layout
    char* ws = (char*)d_ws;
    size_t off = 0;
    __hip_bfloat16* Kw = (__hip_bfloat16*)(ws + off); off += CTOTAL * 2;          // 16 MB
    float* qinv  = (float*)(ws + off); off += (size_t)QD_ELEMS * 4;
    float* dinv  = (float*)(ws + off); off += (size_t)DD_ELEMS * 4;
    float* qdist = (float*)(ws + off); off += (size_t)QD_ELEMS * 4;
    float* ddist = (float*)(ws + off); off += (size_t)DD_ELEMS * 4;
    unsigned int* cmax = (unsigned int*)(ws + off); off += NB * 4;
    float* uvec  = (float*)(ws + off); off += (size_t)QD_ELEMS * 4;
    float* vvec  = (float*)(ws + off); off += (size_t)DD_ELEMS * 4;
    float* part  = (float*)(ws + off); off += NB * 4 * 4;

    hipMemsetAsync(cmax, 0, NB * 4, stream);

    rownorm_kernel<<<QD_ELEMS / 4, 256, 0, stream>>>(qe, qinv, QD_ELEMS);
    rownorm_kernel<<<DD_ELEMS / 4, 256, 0, stream>>>(de, dinv, DD_ELEMS);

    mass_kernel<<<NB, 256, 0, stream>>>(qmask, qdist, LQ);
    mass_kernel<<<NB, 256, 0, stream>>>(dmask, ddist, LD);

    dim3 ggrid(LD / 64, LQ / 64, NB);
    gemm_c_kernel<<<ggrid, 256, 0, stream>>>(qe, de, qinv, dinv, Cout, cmax);

    expk_kernel<<<(CTOTAL / 4) / 256, 256, 0, stream>>>((const float4*)Cout, cmax, (ushort4*)Kw);

    sinkhorn_kernel<<<NB, 1024, 0, stream>>>(Kw, qdist, ddist, nit, uvec, vvec);

    dim3 tgrid(4, NB);
    tdist_kernel<<<tgrid, 256, 0, stream>>>(Cout, Kw, uvec, vvec, Tout, part);

    final_dist_kernel<<<1, 64, 0, stream>>>(part, dist);
}